// Round 9
// baseline (329.553 us; speedup 1.0000x reference)
//
#include <hip/hip_runtime.h>

// Biaffine: B=8, L=512, H=768, O=12
// inputs (B,L,H) fp32 ; weight1 (H,O,H) fp32 ; weight2 (2H+1,O) fp32 ;
// mask (B,L) int32 ; out (B,O,L,L) FLOAT32.
//
// R8: 281 us. gemm1 79 us @ 734 TF, MfmaUtil 15%, VALU 33%, HBM 5% =>
// latency-bound on the serialized GLDS->barrier->ds_read->MFMA chain
// (6 K-iters, ~1.6 blocks/CU). R9: double-buffered GLDS (prefetch k+1
// overlaps compute on k), BK=64 + mfma_scale 32x32x64 to keep LDS at 32 KB
// (2 bufs x (A 8KB + B 8KB)). Same total FLOPs / ds_read bytes as R8.

#define NEGV 1e12f

typedef __attribute__((ext_vector_type(16))) float f32x16;
typedef __attribute__((ext_vector_type(8)))  int   i32x8;

// ---- float -> OCP e4m3fn (flush |v|<2^-6 to 0, round-half-up, sat 448) ----
__device__ __forceinline__ unsigned char f2fp8(float f) {
    union { float f; unsigned u; } c; c.f = f;
    unsigned s = (c.u >> 24) & 0x80;
    unsigned a = c.u & 0x7FFFFFFF;
    if (a < 0x3C800000u) return (unsigned char)s;        // |v| < 2^-6 -> 0
    a += 0x80000;                                        // round at bit 20
    int e = (int)(a >> 23) - 127;
    unsigned m = (a >> 20) & 7;
    if (e > 8 || (e == 8 && m == 7)) return (unsigned char)(s | 0x7E);  // sat 448
    return (unsigned char)(s | ((e + 7) << 3) | m);
}

// global->LDS async copy, 16B per lane; LDS dest is wave-uniform base + lane*16
#define GLDS(gp, lp) __builtin_amdgcn_global_load_lds( \
    (__attribute__((address_space(1))) void*)(gp),     \
    (__attribute__((address_space(3))) void*)(lp), 16, 0, 0)

// ---------------- cast inputs fp32 -> fp8 ----------------
__global__ void cast_a_kernel(const float* __restrict__ in,
                              unsigned char* __restrict__ out, int n4) {
    int i = blockIdx.x * blockDim.x + threadIdx.x;
    if (i < n4) {
        float4 v = ((const float4*)in)[i];
        uchar4 o;
        o.x = f2fp8(v.x); o.y = f2fp8(v.y); o.z = f2fp8(v.z); o.w = f2fp8(v.w);
        ((uchar4*)out)[i] = o;
    }
}

// ---- transpose weight1 (768 x 9216) -> W1T (9216 x 768) fp8, pre-scaled x16 ----
__global__ void transpose_w1_kernel(const float* __restrict__ w1,
                                    unsigned char* __restrict__ w1t) {
    __shared__ float t[64][65];
    const int n0 = blockIdx.x * 64;    // 9216/64 = 144
    const int i0 = blockIdx.y * 64;    // 768/64  = 12
    const int c  = threadIdx.x & 63;
    const int r4 = threadIdx.x >> 6;   // 0..3
    #pragma unroll
    for (int p = 0; p < 16; ++p) {
        int il = p * 4 + r4;
        t[il][c] = w1[(size_t)(i0 + il) * 9216 + n0 + c];
    }
    __syncthreads();
    #pragma unroll
    for (int p = 0; p < 16; ++p) {
        int nl = p * 4 + r4;
        w1t[(size_t)(n0 + nl) * 768 + i0 + c] = f2fp8(t[c][nl] * 16.0f);
    }
}

// ---------------- lin_i / lin_j (inputs @ wa, inputs @ wb), fp32 ----------------
__global__ void lin_kernel(const float* __restrict__ x, const float* __restrict__ w2,
                           float* __restrict__ li, float* __restrict__ lj) {
    int t = blockIdx.x * blockDim.x + threadIdx.x;
    if (t >= 4096 * 12) return;
    int bx = t / 12, o = t % 12;
    const float4* xp4 = (const float4*)(x + (size_t)bx * 768);
    float sa = 0.f, sb = 0.f;
    for (int h4 = 0; h4 < 192; ++h4) {
        float4 v = xp4[h4];
        int h = h4 * 4;
        sa += v.x * w2[h * 12 + o]        + v.y * w2[(h + 1) * 12 + o]
            + v.z * w2[(h + 2) * 12 + o]  + v.w * w2[(h + 3) * 12 + o];
        sb += v.x * w2[(768 + h) * 12 + o]       + v.y * w2[(769 + h) * 12 + o]
            + v.z * w2[(770 + h) * 12 + o]       + v.w * w2[(771 + h) * 12 + o];
    }
    li[t] = sa; lj[t] = sb;
}

// -------- 128x128 fp8 bt-GEMM, BK=64, double-buffered GLDS, 32x32x64 MFMA --------
// A: 128 rows, pitch lda (bytes), K-contiguous. B: 128 rows (N dim), pitch ldb.
// LDS: per buffer, row r = 64 B = 4 slots of 16 B; slot s holds chunk s^(r&3).
// lds layout: [As0 8K][Bs0 8K][As1 8K][Bs1 8K] = 32 KB.
__device__ __forceinline__ void gemm128_fp8_db(
    const unsigned char* __restrict__ A, int lda,
    const unsigned char* __restrict__ B, int ldb,
    char* lds, f32x16 (&acc)[2][2], int sA, int sB) {
    const int tid  = threadIdx.x;
    const int lane = tid & 63;
    const int wave = tid >> 6;
    // staging: per matrix 512 chunks of 16B; 2 per thread.
    const int cc0 = tid, cc1 = tid + 256;
    const int row0 = cc0 >> 2, g0 = (cc0 & 3) ^ (row0 & 3);
    const int row1 = cc1 >> 2, g1 = (cc1 & 3) ^ (row1 & 3);
    const unsigned char* aS0 = A + (size_t)row0 * lda + g0 * 16;
    const unsigned char* aS1 = A + (size_t)row1 * lda + g1 * 16;
    const unsigned char* bS0 = B + (size_t)row0 * ldb + g0 * 16;
    const unsigned char* bS1 = B + (size_t)row1 * ldb + g1 * 16;
    const int d0 = cc0 * 16, d1 = cc1 * 16;

    // fragment read offsets (within one 8 KB buffer)
    const int wm = (wave >> 1) * 64;
    const int wn = (wave & 1) * 64;
    const int l31 = lane & 31, hl = lane >> 5;
    int offA[2][2], offB[2][2];
    #pragma unroll
    for (int t = 0; t < 2; ++t) {
        const int ra = wm + t * 32 + l31;
        const int rb = wn + t * 32 + l31;
        offA[t][0] = ra * 64 + (((hl * 2)    ) ^ (ra & 3)) * 16;
        offA[t][1] = ra * 64 + (((hl * 2) + 1) ^ (ra & 3)) * 16;
        offB[t][0] = rb * 64 + (((hl * 2)    ) ^ (rb & 3)) * 16;
        offB[t][1] = rb * 64 + (((hl * 2) + 1) ^ (rb & 3)) * 16;
    }

    // prologue: stage tile 0 into buffer 0
    GLDS(aS0, lds + d0); GLDS(aS1, lds + d1);
    GLDS(bS0, lds + 8192 + d0); GLDS(bS1, lds + 8192 + d1);

    #pragma unroll
    for (int it = 0; it < 12; ++it) {
        char* cur = lds + (it & 1) * 16384;
        char* nxt = lds + ((it & 1) ^ 1) * 16384;
        __syncthreads();   // staging of cur complete; prior reads of nxt done
        if (it + 1 < 12) { // prefetch next tile, overlapped with compute below
            const int kk = (it + 1) * 64;
            GLDS(aS0 + kk, nxt + d0); GLDS(aS1 + kk, nxt + d1);
            GLDS(bS0 + kk, nxt + 8192 + d0); GLDS(bS1 + kk, nxt + 8192 + d1);
        }
        i32x8 af[2], bf[2];
        #pragma unroll
        for (int t = 0; t < 2; ++t) {
            const uint4 lo = *(const uint4*)(cur + offA[t][0]);
            const uint4 hi = *(const uint4*)(cur + offA[t][1]);
            af[t][0] = lo.x; af[t][1] = lo.y; af[t][2] = lo.z; af[t][3] = lo.w;
            af[t][4] = hi.x; af[t][5] = hi.y; af[t][6] = hi.z; af[t][7] = hi.w;
        }
        #pragma unroll
        for (int t = 0; t < 2; ++t) {
            const uint4 lo = *(const uint4*)(cur + 8192 + offB[t][0]);
            const uint4 hi = *(const uint4*)(cur + 8192 + offB[t][1]);
            bf[t][0] = lo.x; bf[t][1] = lo.y; bf[t][2] = lo.z; bf[t][3] = lo.w;
            bf[t][4] = hi.x; bf[t][5] = hi.y; bf[t][6] = hi.z; bf[t][7] = hi.w;
        }
        #pragma unroll
        for (int tm = 0; tm < 2; ++tm)
            #pragma unroll
            for (int tn = 0; tn < 2; ++tn)
                acc[tm][tn] = __builtin_amdgcn_mfma_scale_f32_32x32x64_f8f6f4(
                    af[tm], bf[tn], acc[tm][tn], 0, 0, 0, sA, 0, sB);
    }
}

// ---- GEMM1: U[bx, n] = A(4096x768) x W1T(9216x768)^T, fp8 out pitch 9216 ----
__global__ __launch_bounds__(256) void gemm1_kernel(
    const unsigned char* __restrict__ A8,
    const unsigned char* __restrict__ W8,
    unsigned char* __restrict__ U) {
    __shared__ __align__(16) char lds[4 * 8192];
    const int m0 = blockIdx.x * 128;  // 32 tiles
    const int n0 = blockIdx.y * 128;  // 72 tiles
    f32x16 acc[2][2] = {};
    gemm128_fp8_db(A8 + (size_t)m0 * 768, 768, W8 + (size_t)n0 * 768, 768,
                   lds, acc, 0x7F7F7F7F, 0x7B7B7B7B);  // W pre-scaled x16 -> sB=2^-4
    const int lane = threadIdx.x & 63;
    const int wave = threadIdx.x >> 6;
    const int wm = (wave >> 1) * 64, wn = (wave & 1) * 64;
    const int l31 = lane & 31, hl = lane >> 5;
    #pragma unroll
    for (int tm = 0; tm < 2; ++tm)
        #pragma unroll
        for (int tn = 0; tn < 2; ++tn)
            #pragma unroll
            for (int rg = 0; rg < 4; ++rg)
                #pragma unroll
                for (int rr = 0; rr < 4; ++rr) {
                    const int m = m0 + wm + tm * 32 + rr + rg * 8 + hl * 4;
                    const int n = n0 + wn + tn * 32 + l31;
                    U[(size_t)m * 9216 + n] = f2fp8(acc[tm][tn][rg * 4 + rr]);
                }
}

// ---- GEMM2 + epilogue: out[b,o,x,y] (fp32), z = b*12+o ----
__global__ __launch_bounds__(256) void gemm2_kernel(
    const unsigned char* __restrict__ U,
    const unsigned char* __restrict__ A8,
    const float* __restrict__ li,
    const float* __restrict__ lj,
    const float* __restrict__ w2,
    const int* __restrict__ mask,
    float* __restrict__ out) {
    __shared__ __align__(16) char lds[4 * 8192];
    const int bo = blockIdx.z;           // 0..95
    const int b = bo / 12, o = bo % 12;
    const int x0 = blockIdx.x * 128;
    const int y0 = blockIdx.y * 128;
    f32x16 acc[2][2] = {};
    gemm128_fp8_db(U + (size_t)(b * 512 + x0) * 9216 + (size_t)o * 768, 9216,
                   A8 + (size_t)(b * 512 + y0) * 768, 768,
                   lds, acc, 0x7F7F7F7F, 0x7F7F7F7F);
    const float bias = w2[1536 * 12 + o];
    float* outp = out + ((size_t)bo) * 512 * 512;
    const int lane = threadIdx.x & 63;
    const int wave = threadIdx.x >> 6;
    const int wm = (wave >> 1) * 64, wn = (wave & 1) * 64;
    const int l31 = lane & 31, hl = lane >> 5;
    float ljv[2]; int mcv[2];
    #pragma unroll
    for (int tn = 0; tn < 2; ++tn) {
        const int y = y0 + wn + tn * 32 + l31;
        ljv[tn] = lj[(size_t)(b * 512 + y) * 12 + o];
        mcv[tn] = mask[b * 512 + y];
    }
    #pragma unroll
    for (int tm = 0; tm < 2; ++tm)
        #pragma unroll
        for (int rg = 0; rg < 4; ++rg)
            #pragma unroll
            for (int rr = 0; rr < 4; ++rr) {
                const int x = x0 + wm + tm * 32 + rr + rg * 8 + hl * 4;
                const float liv = li[(size_t)(b * 512 + x) * 12 + o];
                const int mr = mask[b * 512 + x];
                #pragma unroll
                for (int tn = 0; tn < 2; ++tn) {
                    const int y = y0 + wn + tn * 32 + l31;
                    float v = acc[tm][tn][rg * 4 + rr] + liv + ljv[tn] + bias;
                    if (!(mr & mcv[tn])) v = -NEGV;   // row or col masked -> -1e12
                    if (x > y)           v -= NEGV;   // strict lower tri -> extra -1e12
                    outp[(size_t)x * 512 + y] = v;
                }
            }
}

extern "C" void kernel_launch(void* const* d_in, const int* in_sizes, int n_in,
                              void* d_out, int out_size, void* d_ws, size_t ws_size,
                              hipStream_t stream) {
    const float* inputs = (const float*)d_in[0];
    const float* w1     = (const float*)d_in[1];
    const float* w2     = (const float*)d_in[2];
    const int*   mask   = (const int*)d_in[3];
    float* outp = (float*)d_out;

    // workspace layout (46.1 MB used; ws_size = 384 MiB per R6 fill counters)
    char* ws = (char*)d_ws;
    float* li         = (float*)(ws + 0);                  //    196,608 B
    float* lj         = (float*)(ws + 196608);             //    196,608 B
    unsigned char* A8 = (unsigned char*)(ws + 393216);     //  3,145,728 B
    unsigned char* W8 = (unsigned char*)(ws + 3538944);    //  7,077,888 B
    unsigned char* U8 = (unsigned char*)(ws + 10616832);   // 37,748,736 B -> ends 48,365,568

    cast_a_kernel<<<3072, 256, 0, stream>>>(inputs, A8, 786432);
    lin_kernel<<<192, 256, 0, stream>>>(inputs, w2, li, lj);
    transpose_w1_kernel<<<dim3(144, 12), 256, 0, stream>>>(w1, W8);
    gemm1_kernel<<<dim3(32, 72), 256, 0, stream>>>(A8, W8, U8);
    gemm2_kernel<<<dim3(4, 4, 96), 256, 0, stream>>>(U8, A8, li, lj, w2, mask, outp);
}